// Round 3
// baseline (581.704 us; speedup 1.0000x reference)
//
#include <hip/hip_runtime.h>
#include <hip/hip_fp16.h>

#define N_NODES   100000
#define N_EDGES   1600000
#define NUM_GRAPHS 128
#define HID       64

// ---------------------------------------------------------------- utilities

__device__ __forceinline__ int wave_incl_scan(int v, int lane) {
  #pragma unroll
  for (int d = 1; d < 64; d <<= 1) {
    int t = __shfl_up(v, d, 64);
    if (lane >= d) v += t;
  }
  return v;
}

__global__ void k_zero(int* __restrict__ p, int n) {
  int i = blockIdx.x * blockDim.x + threadIdx.x;
  if (i < n) p[i] = 0;
}

// x (f32) -> fp16, vectorized
__global__ void k_f2h(const float* __restrict__ in, __half* __restrict__ out, int n4) {
  int i = blockIdx.x * blockDim.x + threadIdx.x;
  if (i >= n4) return;
  float4 v = ((const float4*)in)[i];
  __half2 a = __floats2half2_rn(v.x, v.y);
  __half2 b = __floats2half2_rn(v.z, v.w);
  ((__half2*)out)[2 * i]     = a;
  ((__half2*)out)[2 * i + 1] = b;
}

// ---------------------------------------------------------------- CSR build

__global__ void k_count(const int* __restrict__ dst, int* __restrict__ counts) {
  int e = blockIdx.x * blockDim.x + threadIdx.x;
  if (e < N_EDGES) atomicAdd(&counts[dst[e]], 1);
}

__global__ void k_dinv(const int* __restrict__ counts, float* __restrict__ dinv) {
  int v = blockIdx.x * blockDim.x + threadIdx.x;
  if (v < N_NODES) dinv[v] = rsqrtf((float)(counts[v] + 1));  // +1 self-loop
}

__global__ void k_alloc(const int* __restrict__ counts, int* __restrict__ row_off,
                        int* __restrict__ total) {
  int i = blockIdx.x * blockDim.x + threadIdx.x;
  int lane = threadIdx.x & 63;
  int c = (i < N_NODES) ? counts[i] : 0;
  int incl = wave_incl_scan(c, lane);
  int base = 0;
  if (lane == 63) base = atomicAdd(total, incl);
  base = __shfl(base, 63, 64);
  if (i < N_NODES) row_off[i] = base + incl - c;
}

__global__ void k_fill(const int* __restrict__ src, const int* __restrict__ dst,
                       const float* __restrict__ dinv, const int* __restrict__ row_off,
                       int* __restrict__ fill_cnt, int2* __restrict__ csr) {
  int e = blockIdx.x * blockDim.x + threadIdx.x;
  if (e >= N_EDGES) return;
  int s = src[e], d = dst[e];
  int p = atomicAdd(&fill_cnt[d], 1);
  int j = row_off[d] + p;
  csr[j] = make_int2(s, __float_as_int(dinv[s] * dinv[d]));
}

// ---------------------------------------------------------------- fused agg + GEMM
// Per 256-thread block: 64 nodes.
// Phase 1: wave w aggregates nodes [w*16, w*16+16): agg[v][lane] =
//          dinv[v]^2*h[v][lane] + sum_e norm_e*h[src_e][lane]  -> LDS sA
// Phase 2: tile GEMM sA[64x64] @ sW[64x64], + bias, ReLU, fp16 store.
// Uses agg(h@W) == agg(h)@W (aggregation is linear).

__global__ __launch_bounds__(256) void k_agg_gemm(const __half* __restrict__ h,
                                                  const int* __restrict__ row_off,
                                                  const int* __restrict__ counts,
                                                  const int2* __restrict__ csr,
                                                  const float* __restrict__ dinv,
                                                  const float* __restrict__ W,
                                                  const float* __restrict__ bias,
                                                  __half* __restrict__ out) {
  __shared__ float sW[64 * 64];
  __shared__ float sA[64][65];
  int tid = threadIdx.x;
  int wid = tid >> 6, lane = tid & 63;

  #pragma unroll
  for (int i = tid; i < 1024; i += 256)
    ((float4*)sW)[i] = ((const float4*)W)[i];

  int row0 = blockIdx.x * 64;
  // ---- phase 1: aggregate 16 nodes per wave
  for (int n = 0; n < 16; ++n) {
    int r = wid * 16 + n;
    int v = row0 + r;
    float acc = 0.0f;
    if (v < N_NODES) {
      float dv = dinv[v];
      acc = dv * dv * __half2float(h[(size_t)v * HID + lane]);
      int o = row_off[v], c = counts[v];
      int i = 0;
      for (; i + 4 <= c; i += 4) {
        int2 p0 = csr[o + i + 0];
        int2 p1 = csr[o + i + 1];
        int2 p2 = csr[o + i + 2];
        int2 p3 = csr[o + i + 3];
        float h0 = __half2float(h[(size_t)p0.x * HID + lane]);
        float h1 = __half2float(h[(size_t)p1.x * HID + lane]);
        float h2 = __half2float(h[(size_t)p2.x * HID + lane]);
        float h3 = __half2float(h[(size_t)p3.x * HID + lane]);
        acc += __int_as_float(p0.y) * h0;
        acc += __int_as_float(p1.y) * h1;
        acc += __int_as_float(p2.y) * h2;
        acc += __int_as_float(p3.y) * h3;
      }
      for (; i < c; ++i) {
        int2 p = csr[o + i];
        acc += __int_as_float(p.y) * __half2float(h[(size_t)p.x * HID + lane]);
      }
    }
    sA[r][lane] = acc;
  }
  __syncthreads();

  // ---- phase 2: 64x64 tile GEMM from LDS
  int tr = (tid >> 4) << 2;
  int tc = (tid & 15) << 2;
  float acc[4][4];
  #pragma unroll
  for (int i = 0; i < 4; ++i)
    #pragma unroll
    for (int j = 0; j < 4; ++j) acc[i][j] = 0.f;
  #pragma unroll 8
  for (int k = 0; k < 64; ++k) {
    float4 w = *(const float4*)&sW[k * 64 + tc];
    float a0 = sA[tr + 0][k], a1 = sA[tr + 1][k], a2 = sA[tr + 2][k], a3 = sA[tr + 3][k];
    acc[0][0] += a0 * w.x; acc[0][1] += a0 * w.y; acc[0][2] += a0 * w.z; acc[0][3] += a0 * w.w;
    acc[1][0] += a1 * w.x; acc[1][1] += a1 * w.y; acc[1][2] += a1 * w.z; acc[1][3] += a1 * w.w;
    acc[2][0] += a2 * w.x; acc[2][1] += a2 * w.y; acc[2][2] += a2 * w.z; acc[2][3] += a2 * w.w;
    acc[3][0] += a3 * w.x; acc[3][1] += a3 * w.y; acc[3][2] += a3 * w.z; acc[3][3] += a3 * w.w;
  }
  float b0 = bias[tc + 0], b1 = bias[tc + 1], b2 = bias[tc + 2], b3 = bias[tc + 3];
  #pragma unroll
  for (int i = 0; i < 4; ++i) {
    int row = row0 + tr + i;
    if (row < N_NODES) {
      __half2 p0 = __floats2half2_rn(fmaxf(acc[i][0] + b0, 0.f), fmaxf(acc[i][1] + b1, 0.f));
      __half2 p1 = __floats2half2_rn(fmaxf(acc[i][2] + b2, 0.f), fmaxf(acc[i][3] + b3, 0.f));
      *(__half2*)(out + (size_t)row * HID + tc)     = p0;
      *(__half2*)(out + (size_t)row * HID + tc + 2) = p1;
    }
  }
}

// ---------------------------------------------------------------- pooling + MLP
// batch sorted -> segmented reduction, one atomic flush per run boundary.

#define POOL_CHUNK 32

__global__ __launch_bounds__(256) void k_pool(const __half* __restrict__ h,
                                              const int* __restrict__ batch,
                                              float* __restrict__ pooled,
                                              int* __restrict__ pcnt) {
  int wid = threadIdx.x >> 6, lane = threadIdx.x & 63;
  int w = blockIdx.x * (blockDim.x >> 6) + wid;
  int v0 = w * POOL_CHUNK;
  if (v0 >= N_NODES) return;
  int vend = min(v0 + POOL_CHUNK, N_NODES);
  int g = batch[v0];
  float acc = 0.0f;
  int cnt = 0;
  for (int v = v0; v < vend; ++v) {
    int gv = batch[v];
    if (gv != g) {
      atomicAdd(&pooled[g * HID + lane], acc);
      if (lane == 0) atomicAdd(&pcnt[g], cnt);
      g = gv; acc = 0.0f; cnt = 0;
    }
    acc += __half2float(h[(size_t)v * HID + lane]);
    ++cnt;
  }
  atomicAdd(&pooled[g * HID + lane], acc);
  if (lane == 0) atomicAdd(&pcnt[g], cnt);
}

__global__ void k_mlp(const float* __restrict__ pooled, const int* __restrict__ pcnt,
                      const float* __restrict__ fc1w, const float* __restrict__ fc1b,
                      const float* __restrict__ fc2w, const float* __restrict__ fc2b,
                      float* __restrict__ out) {
  int g = threadIdx.x;
  if (g >= NUM_GRAPHS) return;
  float inv = 1.0f / fmaxf((float)pcnt[g], 1.0f);
  float hid[10];
  #pragma unroll
  for (int j = 0; j < 10; ++j) hid[j] = fc1b[j];
  for (int k = 0; k < HID; ++k) {
    float p = pooled[g * HID + k] * inv;
    #pragma unroll
    for (int j = 0; j < 10; ++j) hid[j] += p * fc1w[k * 10 + j];
  }
  float o = fc2b[0];
  #pragma unroll
  for (int j = 0; j < 10; ++j) o += fmaxf(hid[j], 0.0f) * fc2w[j];
  out[g] = o;
}

// ---------------------------------------------------------------- launch

extern "C" void kernel_launch(void* const* d_in, const int* in_sizes, int n_in,
                              void* d_out, int out_size, void* d_ws, size_t ws_size,
                              hipStream_t stream) {
  const float* x    = (const float*)d_in[0];
  const int*   ei   = (const int*)d_in[1];      // [2, E]
  const int*   batch= (const int*)d_in[2];
  const float* W1   = (const float*)d_in[3];
  const float* b1   = (const float*)d_in[4];
  const float* W2   = (const float*)d_in[5];
  const float* b2   = (const float*)d_in[6];
  const float* W3   = (const float*)d_in[7];
  const float* b3   = (const float*)d_in[8];
  const float* fc1w = (const float*)d_in[9];
  const float* fc1b = (const float*)d_in[10];
  const float* fc2w = (const float*)d_in[11];
  const float* fc2b = (const float*)d_in[12];

  const int* e_src = ei;
  const int* e_dst = ei + N_EDGES;

  // workspace layout
  char* ws = (char*)d_ws;
  int* counts   = (int*)ws;                  // [100000]
  int* fill_cnt = counts + 100000;           // [100000]
  int* total    = counts + 200000;           // [1] (+pad)
  int* pcnt     = counts + 200064;           // [128]
  float* pooled = (float*)(counts + 200192); // [8192]
  const int ZERO_N = 208384;
  size_t off = (size_t)ZERO_N * 4;
  auto alignup = [](size_t o, size_t a) { return (o + a - 1) / a * a; };
  off = alignup(off, 256);
  float* dinv = (float*)(ws + off);  off += (size_t)N_NODES * 4;   off = alignup(off, 256);
  int* row_off = (int*)(ws + off);   off += (size_t)N_NODES * 4;   off = alignup(off, 256);
  int2* csr = (int2*)(ws + off);     off += (size_t)N_EDGES * 8;   off = alignup(off, 256);
  __half* xh  = (__half*)(ws + off); off += (size_t)N_NODES * HID * 2; off = alignup(off, 256);
  __half* h_a = (__half*)(ws + off); off += (size_t)N_NODES * HID * 2; off = alignup(off, 256);
  __half* h_b = (__half*)(ws + off); off += (size_t)N_NODES * HID * 2;
  (void)ws_size; (void)in_sizes; (void)n_in; (void)out_size;

  const int TB = 256;
  // input conversion + CSR build
  k_zero <<<(ZERO_N + TB - 1) / TB, TB, 0, stream>>>(counts, ZERO_N);
  k_f2h  <<<(N_NODES * HID / 4 + TB - 1) / TB, TB, 0, stream>>>(x, xh, N_NODES * HID / 4);
  k_count<<<(N_EDGES + TB - 1) / TB, TB, 0, stream>>>(e_dst, counts);
  k_dinv <<<(N_NODES + TB - 1) / TB, TB, 0, stream>>>(counts, dinv);
  k_alloc<<<(N_NODES + TB - 1) / TB, TB, 0, stream>>>(counts, row_off, total);
  k_fill <<<(N_EDGES + TB - 1) / TB, TB, 0, stream>>>(e_src, e_dst, dinv, row_off, fill_cnt, csr);

  const int FUSED_GRID = (N_NODES + 63) / 64;   // 1563

  k_agg_gemm<<<FUSED_GRID, TB, 0, stream>>>(xh,  row_off, counts, csr, dinv, W1, b1, h_a);
  k_agg_gemm<<<FUSED_GRID, TB, 0, stream>>>(h_a, row_off, counts, csr, dinv, W2, b2, h_b);
  k_agg_gemm<<<FUSED_GRID, TB, 0, stream>>>(h_b, row_off, counts, csr, dinv, W3, b3, h_a);

  const int POOL_GRID = ((N_NODES + POOL_CHUNK - 1) / POOL_CHUNK + 3) / 4;
  k_pool<<<POOL_GRID, TB, 0, stream>>>(h_a, batch, pooled, pcnt);
  k_mlp <<<1, 128, 0, stream>>>(pooled, pcnt, fc1w, fc1b, fc2w, fc2b, (float*)d_out);
}

// Round 4
// 495.480 us; speedup vs baseline: 1.1740x; 1.1740x over previous
//
#include <hip/hip_runtime.h>
#include <hip/hip_fp16.h>

#define N_NODES   100000
#define N_EDGES   1600000
#define NUM_GRAPHS 128
#define HID       64

// ---------------------------------------------------------------- utilities

__device__ __forceinline__ int wave_incl_scan(int v, int lane) {
  #pragma unroll
  for (int d = 1; d < 64; d <<= 1) {
    int t = __shfl_up(v, d, 64);
    if (lane >= d) v += t;
  }
  return v;
}

__global__ void k_zero(int* __restrict__ p, int n) {
  int i = blockIdx.x * blockDim.x + threadIdx.x;
  if (i < n) p[i] = 0;
}

// x (f32) -> fp16, vectorized
__global__ void k_f2h(const float* __restrict__ in, __half* __restrict__ out, int n4) {
  int i = blockIdx.x * blockDim.x + threadIdx.x;
  if (i >= n4) return;
  float4 v = ((const float4*)in)[i];
  ((__half2*)out)[2 * i]     = __floats2half2_rn(v.x, v.y);
  ((__half2*)out)[2 * i + 1] = __floats2half2_rn(v.z, v.w);
}

// ---------------------------------------------------------------- CSR build

__global__ void k_count(const int* __restrict__ dst, int* __restrict__ counts) {
  int e = blockIdx.x * blockDim.x + threadIdx.x;
  if (e < N_EDGES) atomicAdd(&counts[dst[e]], 1);
}

// alloc + dinv fused (both read counts)
__global__ void k_alloc(const int* __restrict__ counts, int* __restrict__ row_off,
                        float* __restrict__ dinv, int* __restrict__ total) {
  int i = blockIdx.x * blockDim.x + threadIdx.x;
  int lane = threadIdx.x & 63;
  int c = (i < N_NODES) ? counts[i] : 0;
  int incl = wave_incl_scan(c, lane);
  int base = 0;
  if (lane == 63) base = atomicAdd(total, incl);
  base = __shfl(base, 63, 64);
  if (i < N_NODES) {
    row_off[i] = base + incl - c;
    dinv[i] = rsqrtf((float)(c + 1));  // +1 self-loop
  }
}

// 4B scatter: only src index. norm recomputed in agg from dinv.
__global__ void k_fill(const int* __restrict__ src, const int* __restrict__ dst,
                       const int* __restrict__ row_off,
                       int* __restrict__ fill_cnt, int* __restrict__ csr_src) {
  int e = blockIdx.x * blockDim.x + threadIdx.x;
  if (e >= N_EDGES) return;
  int s = src[e], d = dst[e];
  int p = atomicAdd(&fill_cnt[d], 1);
  csr_src[row_off[d] + p] = s;
}

// ---------------------------------------------------------------- dense GEMM (fp16 in/out)
// C[100000,64] = A[100000,64] @ W[64,64]; f32 accumulate, bias-free (agg adds it).

__global__ __launch_bounds__(256) void k_gemm(const __half* __restrict__ A,
                                              const float* __restrict__ W,
                                              __half* __restrict__ C) {
  __shared__ float sW[64 * 64];
  __shared__ float sA[64][65];
  int tid = threadIdx.x;
  #pragma unroll
  for (int i = tid; i < 1024; i += 256)
    ((float4*)sW)[i] = ((const float4*)W)[i];
  int row0 = blockIdx.x * 64;
  #pragma unroll
  for (int i = tid; i < 1024; i += 256) {
    int r = i >> 4, c4 = (i & 15) << 2;
    int row = row0 + r;
    if (row < N_NODES) {
      __half2 a = *(const __half2*)(A + (size_t)row * 64 + c4);
      __half2 b = *(const __half2*)(A + (size_t)row * 64 + c4 + 2);
      float2 fa = __half22float2(a), fb = __half22float2(b);
      sA[r][c4 + 0] = fa.x; sA[r][c4 + 1] = fa.y;
      sA[r][c4 + 2] = fb.x; sA[r][c4 + 3] = fb.y;
    } else {
      sA[r][c4 + 0] = 0.f; sA[r][c4 + 1] = 0.f; sA[r][c4 + 2] = 0.f; sA[r][c4 + 3] = 0.f;
    }
  }
  __syncthreads();
  int tr = (tid >> 4) << 2;
  int tc = (tid & 15) << 2;
  float acc[4][4];
  #pragma unroll
  for (int i = 0; i < 4; ++i)
    #pragma unroll
    for (int j = 0; j < 4; ++j) acc[i][j] = 0.f;
  #pragma unroll 8
  for (int k = 0; k < 64; ++k) {
    float4 w = *(const float4*)&sW[k * 64 + tc];
    float a0 = sA[tr + 0][k], a1 = sA[tr + 1][k], a2 = sA[tr + 2][k], a3 = sA[tr + 3][k];
    acc[0][0] += a0 * w.x; acc[0][1] += a0 * w.y; acc[0][2] += a0 * w.z; acc[0][3] += a0 * w.w;
    acc[1][0] += a1 * w.x; acc[1][1] += a1 * w.y; acc[1][2] += a1 * w.z; acc[1][3] += a1 * w.w;
    acc[2][0] += a2 * w.x; acc[2][1] += a2 * w.y; acc[2][2] += a2 * w.z; acc[2][3] += a2 * w.w;
    acc[3][0] += a3 * w.x; acc[3][1] += a3 * w.y; acc[3][2] += a3 * w.z; acc[3][3] += a3 * w.w;
  }
  #pragma unroll
  for (int i = 0; i < 4; ++i) {
    int row = row0 + tr + i;
    if (row < N_NODES) {
      *(__half2*)(C + (size_t)row * 64 + tc)     = __floats2half2_rn(acc[i][0], acc[i][1]);
      *(__half2*)(C + (size_t)row * 64 + tc + 2) = __floats2half2_rn(acc[i][2], acc[i][3]);
    }
  }
}

// ---------------------------------------------------------------- aggregation
// out[v] = relu( dv * ( sum_e dinv[s]*hw[s] + dv*hw[v] ) + b ), one wave per node.

__global__ __launch_bounds__(256) void k_agg(const __half* __restrict__ hw,
                                             const int* __restrict__ row_off,
                                             const int* __restrict__ counts,
                                             const int* __restrict__ csr_src,
                                             const float* __restrict__ dinv,
                                             const float* __restrict__ bias,
                                             __half* __restrict__ out) {
  int wid = threadIdx.x >> 6;
  int lane = threadIdx.x & 63;
  int v = blockIdx.x * (blockDim.x >> 6) + wid;
  if (v >= N_NODES) return;
  float dv = dinv[v];
  float acc = dv * __half2float(hw[(size_t)v * HID + lane]);
  int o = row_off[v], c = counts[v];
  int i = 0;
  for (; i + 4 <= c; i += 4) {
    int s0 = csr_src[o + i + 0];
    int s1 = csr_src[o + i + 1];
    int s2 = csr_src[o + i + 2];
    int s3 = csr_src[o + i + 3];
    float d0 = dinv[s0], d1 = dinv[s1], d2 = dinv[s2], d3 = dinv[s3];
    float h0 = __half2float(hw[(size_t)s0 * HID + lane]);
    float h1 = __half2float(hw[(size_t)s1 * HID + lane]);
    float h2 = __half2float(hw[(size_t)s2 * HID + lane]);
    float h3 = __half2float(hw[(size_t)s3 * HID + lane]);
    acc += d0 * h0;
    acc += d1 * h1;
    acc += d2 * h2;
    acc += d3 * h3;
  }
  for (; i < c; ++i) {
    int s = csr_src[o + i];
    acc += dinv[s] * __half2float(hw[(size_t)s * HID + lane]);
  }
  float r = fmaxf(dv * acc + bias[lane], 0.0f);
  out[(size_t)v * HID + lane] = __float2half_rn(r);
}

// ---------------------------------------------------------------- pooling + MLP

#define POOL_CHUNK 32

__global__ __launch_bounds__(256) void k_pool(const __half* __restrict__ h,
                                              const int* __restrict__ batch,
                                              float* __restrict__ pooled,
                                              int* __restrict__ pcnt) {
  int wid = threadIdx.x >> 6, lane = threadIdx.x & 63;
  int w = blockIdx.x * (blockDim.x >> 6) + wid;
  int v0 = w * POOL_CHUNK;
  if (v0 >= N_NODES) return;
  int vend = min(v0 + POOL_CHUNK, N_NODES);
  int g = batch[v0];
  float acc = 0.0f;
  int cnt = 0;
  for (int v = v0; v < vend; ++v) {
    int gv = batch[v];
    if (gv != g) {
      atomicAdd(&pooled[g * HID + lane], acc);
      if (lane == 0) atomicAdd(&pcnt[g], cnt);
      g = gv; acc = 0.0f; cnt = 0;
    }
    acc += __half2float(h[(size_t)v * HID + lane]);
    ++cnt;
  }
  atomicAdd(&pooled[g * HID + lane], acc);
  if (lane == 0) atomicAdd(&pcnt[g], cnt);
}

__global__ void k_mlp(const float* __restrict__ pooled, const int* __restrict__ pcnt,
                      const float* __restrict__ fc1w, const float* __restrict__ fc1b,
                      const float* __restrict__ fc2w, const float* __restrict__ fc2b,
                      float* __restrict__ out) {
  int g = threadIdx.x;
  if (g >= NUM_GRAPHS) return;
  float inv = 1.0f / fmaxf((float)pcnt[g], 1.0f);
  float hid[10];
  #pragma unroll
  for (int j = 0; j < 10; ++j) hid[j] = fc1b[j];
  for (int k = 0; k < HID; ++k) {
    float p = pooled[g * HID + k] * inv;
    #pragma unroll
    for (int j = 0; j < 10; ++j) hid[j] += p * fc1w[k * 10 + j];
  }
  float o = fc2b[0];
  #pragma unroll
  for (int j = 0; j < 10; ++j) o += fmaxf(hid[j], 0.0f) * fc2w[j];
  out[g] = o;
}

// ---------------------------------------------------------------- launch

extern "C" void kernel_launch(void* const* d_in, const int* in_sizes, int n_in,
                              void* d_out, int out_size, void* d_ws, size_t ws_size,
                              hipStream_t stream) {
  const float* x    = (const float*)d_in[0];
  const int*   ei   = (const int*)d_in[1];      // [2, E]
  const int*   batch= (const int*)d_in[2];
  const float* W1   = (const float*)d_in[3];
  const float* b1   = (const float*)d_in[4];
  const float* W2   = (const float*)d_in[5];
  const float* b2   = (const float*)d_in[6];
  const float* W3   = (const float*)d_in[7];
  const float* b3   = (const float*)d_in[8];
  const float* fc1w = (const float*)d_in[9];
  const float* fc1b = (const float*)d_in[10];
  const float* fc2w = (const float*)d_in[11];
  const float* fc2b = (const float*)d_in[12];

  const int* e_src = ei;
  const int* e_dst = ei + N_EDGES;

  // workspace layout
  char* ws = (char*)d_ws;
  int* counts   = (int*)ws;                  // [100000]
  int* fill_cnt = counts + 100000;           // [100000]
  int* total    = counts + 200000;           // [1] (+pad)
  int* pcnt     = counts + 200064;           // [128]
  float* pooled = (float*)(counts + 200192); // [8192]
  const int ZERO_N = 208384;
  size_t off = (size_t)ZERO_N * 4;
  auto alignup = [](size_t o, size_t a) { return (o + a - 1) / a * a; };
  off = alignup(off, 256);
  float* dinv = (float*)(ws + off);    off += (size_t)N_NODES * 4;       off = alignup(off, 256);
  int* row_off = (int*)(ws + off);     off += (size_t)N_NODES * 4;       off = alignup(off, 256);
  int* csr_src = (int*)(ws + off);     off += (size_t)N_EDGES * 4;       off = alignup(off, 256);
  __half* xh  = (__half*)(ws + off);   off += (size_t)N_NODES * HID * 2; off = alignup(off, 256);
  __half* h_a = (__half*)(ws + off);   off += (size_t)N_NODES * HID * 2; off = alignup(off, 256);
  __half* h_b = (__half*)(ws + off);   off += (size_t)N_NODES * HID * 2;
  (void)ws_size; (void)in_sizes; (void)n_in; (void)out_size;

  const int TB = 256;
  k_zero <<<(ZERO_N + TB - 1) / TB, TB, 0, stream>>>(counts, ZERO_N);
  k_f2h  <<<(N_NODES * HID / 4 + TB - 1) / TB, TB, 0, stream>>>(x, xh, N_NODES * HID / 4);
  k_count<<<(N_EDGES + TB - 1) / TB, TB, 0, stream>>>(e_dst, counts);
  k_alloc<<<(N_NODES + TB - 1) / TB, TB, 0, stream>>>(counts, row_off, dinv, total);
  k_fill <<<(N_EDGES + TB - 1) / TB, TB, 0, stream>>>(e_src, e_dst, row_off, fill_cnt, csr_src);

  const int GEMM_GRID = (N_NODES + 63) / 64;   // 1563
  const int AGG_GRID  = (N_NODES + 3) / 4;     // 25000

  // layer 1
  k_gemm<<<GEMM_GRID, TB, 0, stream>>>(xh, W1, h_a);
  k_agg <<<AGG_GRID, TB, 0, stream>>>(h_a, row_off, counts, csr_src, dinv, b1, h_b);
  // layer 2
  k_gemm<<<GEMM_GRID, TB, 0, stream>>>(h_b, W2, h_a);
  k_agg <<<AGG_GRID, TB, 0, stream>>>(h_a, row_off, counts, csr_src, dinv, b2, h_b);
  // layer 3
  k_gemm<<<GEMM_GRID, TB, 0, stream>>>(h_b, W3, h_a);
  k_agg <<<AGG_GRID, TB, 0, stream>>>(h_a, row_off, counts, csr_src, dinv, b3, h_b);

  // pool + MLP
  const int POOL_GRID = ((N_NODES + POOL_CHUNK - 1) / POOL_CHUNK + 3) / 4;
  k_pool<<<POOL_GRID, TB, 0, stream>>>(h_b, batch, pooled, pcnt);
  k_mlp <<<1, 128, 0, stream>>>(pooled, pcnt, fc1w, fc1b, fc2w, fc2b, (float*)d_out);
}

// Round 5
// 354.138 us; speedup vs baseline: 1.6426x; 1.3991x over previous
//
#include <hip/hip_runtime.h>
#include <hip/hip_fp16.h>

#define N_NODES   100000
#define N_EDGES   1600000
#define NUM_GRAPHS 128
#define HID       64

#define NB   512          // buckets (node-space partitions)
#define NPB  196          // nodes per bucket: ceil(100000/512)=196; buckets 0..510 used
#define NBU  511          // used buckets
#define CPE  3125         // edges per binning chunk: 1600000/512
#define CSR_TOT (N_EDGES + N_NODES)   // CSR includes one self entry per node

// ---------------------------------------------------------------- utilities

__global__ void k_zero(int* __restrict__ p, int n) {
  int i = blockIdx.x * blockDim.x + threadIdx.x;
  if (i < n) p[i] = 0;
}

__global__ void k_f2h(const float* __restrict__ in, __half* __restrict__ out, int n4) {
  int i = blockIdx.x * blockDim.x + threadIdx.x;
  if (i >= n4) return;
  float4 v = ((const float4*)in)[i];
  ((__half2*)out)[2 * i]     = __floats2half2_rn(v.x, v.y);
  ((__half2*)out)[2 * i + 1] = __floats2half2_rn(v.z, v.w);
}

// ---------------------------------------------------------------- bucketed CSR build
// B1a: per-chunk bucket histogram -> H[w][b]
__global__ __launch_bounds__(256) void k_b1a(const int* __restrict__ dst, int* __restrict__ H) {
  __shared__ int hist[NB];
  int w = blockIdx.x, t = threadIdx.x;
  for (int b = t; b < NB; b += 256) hist[b] = 0;
  __syncthreads();
  int e0 = w * CPE;
  for (int i = t; i < CPE; i += 256)
    atomicAdd(&hist[dst[e0 + i] / NPB], 1);
  __syncthreads();
  for (int b = t; b < NB; b += 256) H[w * NB + b] = hist[b];
}

// column sums: S[b] = sum_w H[w][b]
__global__ __launch_bounds__(256) void k_colsum(const int* __restrict__ H, int* __restrict__ S) {
  __shared__ int red[256];
  int b = blockIdx.x, t = threadIdx.x;
  red[t] = H[t * NB + b] + H[(t + 256) * NB + b];
  __syncthreads();
  for (int d = 128; d > 0; d >>= 1) { if (t < d) red[t] += red[t + d]; __syncthreads(); }
  if (t == 0) S[b] = red[0];
}

// exclusive scan over bucket sums -> bstart[0..NB]
__global__ __launch_bounds__(512) void k_bscan(const int* __restrict__ S, int* __restrict__ bstart) {
  __shared__ int sc[NB];
  int t = threadIdx.x;
  int v = S[t];
  sc[t] = v; __syncthreads();
  for (int d = 1; d < NB; d <<= 1) {
    int x = (t >= d) ? sc[t - d] : 0; __syncthreads();
    sc[t] += x; __syncthreads();
  }
  bstart[t] = sc[t] - v;
  if (t == NB - 1) bstart[NB] = sc[t];
}

// per-bucket prefix over w: OT[b][w] = bstart[b] + sum_{w'<w} H[w'][b]
__global__ __launch_bounds__(512) void k_rowscan(const int* __restrict__ H,
                                                 const int* __restrict__ bstart,
                                                 int* __restrict__ OT) {
  __shared__ int sc[NB];
  int b = blockIdx.x, t = threadIdx.x;
  int v = H[t * NB + b];
  sc[t] = v; __syncthreads();
  for (int d = 1; d < NB; d <<= 1) {
    int x = (t >= d) ? sc[t - d] : 0; __syncthreads();
    sc[t] += x; __syncthreads();
  }
  OT[b * NB + t] = bstart[b] + sc[t] - v;
}

// B1b: bin edges into bucket-contiguous staging (contiguous runs per (b,w))
__global__ __launch_bounds__(256) void k_b1b(const int* __restrict__ src,
                                             const int* __restrict__ dst,
                                             const int* __restrict__ OT,
                                             int2* __restrict__ staged) {
  __shared__ int pos[NB];
  int w = blockIdx.x, t = threadIdx.x;
  for (int b = t; b < NB; b += 256) pos[b] = OT[b * NB + w];
  __syncthreads();
  int e0 = w * CPE;
  for (int i = t; i < CPE; i += 256) {
    int s = src[e0 + i], d = dst[e0 + i];
    int p = atomicAdd(&pos[d / NPB], 1);
    staged[p] = make_int2(s, d);
  }
}

// B2a: per-bucket LDS node counts -> monotone row_off (+1 self slot per node) + dinv
__global__ __launch_bounds__(256) void k_b2a(const int2* __restrict__ staged,
                                             const int* __restrict__ bstart,
                                             int* __restrict__ row_off,
                                             float* __restrict__ dinv) {
  __shared__ int cnt[256];
  __shared__ int sc[256];
  int b = blockIdx.x, t = threadIdx.x;
  int nloc = min(NPB, N_NODES - b * NPB);
  cnt[t] = 0;
  __syncthreads();
  int s0 = bstart[b], s1 = bstart[b + 1];
  for (int i = s0 + t; i < s1; i += 256)
    atomicAdd(&cnt[staged[i].y - b * NPB], 1);
  __syncthreads();
  int v = (t < nloc) ? cnt[t] + 1 : 0;   // +1: self-loop CSR entry
  sc[t] = v; __syncthreads();
  for (int d = 1; d < 256; d <<= 1) {
    int x = (t >= d) ? sc[t - d] : 0; __syncthreads();
    sc[t] += x; __syncthreads();
  }
  if (t < nloc) {
    int g = b * NPB + t;
    row_off[g] = bstart[b] + b * NPB + (sc[t] - v);
    dinv[g] = rsqrtf((float)(cnt[t] + 1));   // deg = indeg + self-loop
  }
  if (b == 0 && t == 0) row_off[N_NODES] = CSR_TOT;
}

// B2b: place final (src, norm) entries; self entry first; window is L2-resident
__global__ __launch_bounds__(256) void k_b2b(const int2* __restrict__ staged,
                                             const int* __restrict__ bstart,
                                             const int* __restrict__ row_off,
                                             const float* __restrict__ dinv,
                                             int2* __restrict__ csr) {
  __shared__ int pos[NPB];
  __shared__ float dl[NPB];
  int b = blockIdx.x, t = threadIdx.x;
  int nloc = min(NPB, N_NODES - b * NPB);
  if (t < nloc) {
    int g = b * NPB + t;
    int ro = row_off[g];
    float dv = dinv[g];
    csr[ro] = make_int2(g, __float_as_int(dv * dv));   // self-loop entry
    pos[t] = ro + 1;
    dl[t] = dv;
  }
  __syncthreads();
  int s0 = bstart[b], s1 = bstart[b + 1];
  for (int i = s0 + t; i < s1; i += 256) {
    int2 e = staged[i];
    int l = e.y - b * NPB;
    int p = atomicAdd(&pos[l], 1);
    csr[p] = make_int2(e.x, __float_as_int(dl[l] * dinv[e.x]));
  }
}

// ---------------------------------------------------------------- dense GEMM (fp16 in/out)

__global__ __launch_bounds__(256) void k_gemm(const __half* __restrict__ A,
                                              const float* __restrict__ W,
                                              __half* __restrict__ C) {
  __shared__ float sW[64 * 64];
  __shared__ float sA[64][65];
  int tid = threadIdx.x;
  #pragma unroll
  for (int i = tid; i < 1024; i += 256)
    ((float4*)sW)[i] = ((const float4*)W)[i];
  int row0 = blockIdx.x * 64;
  #pragma unroll
  for (int i = tid; i < 1024; i += 256) {
    int r = i >> 4, c4 = (i & 15) << 2;
    int row = row0 + r;
    if (row < N_NODES) {
      __half2 a = *(const __half2*)(A + (size_t)row * 64 + c4);
      __half2 b = *(const __half2*)(A + (size_t)row * 64 + c4 + 2);
      float2 fa = __half22float2(a), fb = __half22float2(b);
      sA[r][c4 + 0] = fa.x; sA[r][c4 + 1] = fa.y;
      sA[r][c4 + 2] = fb.x; sA[r][c4 + 3] = fb.y;
    } else {
      sA[r][c4 + 0] = 0.f; sA[r][c4 + 1] = 0.f; sA[r][c4 + 2] = 0.f; sA[r][c4 + 3] = 0.f;
    }
  }
  __syncthreads();
  int tr = (tid >> 4) << 2;
  int tc = (tid & 15) << 2;
  float acc[4][4];
  #pragma unroll
  for (int i = 0; i < 4; ++i)
    #pragma unroll
    for (int j = 0; j < 4; ++j) acc[i][j] = 0.f;
  #pragma unroll 8
  for (int k = 0; k < 64; ++k) {
    float4 w = *(const float4*)&sW[k * 64 + tc];
    float a0 = sA[tr + 0][k], a1 = sA[tr + 1][k], a2 = sA[tr + 2][k], a3 = sA[tr + 3][k];
    acc[0][0] += a0 * w.x; acc[0][1] += a0 * w.y; acc[0][2] += a0 * w.z; acc[0][3] += a0 * w.w;
    acc[1][0] += a1 * w.x; acc[1][1] += a1 * w.y; acc[1][2] += a1 * w.z; acc[1][3] += a1 * w.w;
    acc[2][0] += a2 * w.x; acc[2][1] += a2 * w.y; acc[2][2] += a2 * w.z; acc[2][3] += a2 * w.w;
    acc[3][0] += a3 * w.x; acc[3][1] += a3 * w.y; acc[3][2] += a3 * w.z; acc[3][3] += a3 * w.w;
  }
  #pragma unroll
  for (int i = 0; i < 4; ++i) {
    int row = row0 + tr + i;
    if (row < N_NODES) {
      *(__half2*)(C + (size_t)row * 64 + tc)     = __floats2half2_rn(acc[i][0], acc[i][1]);
      *(__half2*)(C + (size_t)row * 64 + tc + 2) = __floats2half2_rn(acc[i][2], acc[i][3]);
    }
  }
}

// ---------------------------------------------------------------- aggregation
// out[v] = relu( sum_{i in [row_off[v],row_off[v+1])} norm_i * hw[src_i] + b )
// (self-loop is a regular CSR entry). One wave per node, lane = feature.

__global__ __launch_bounds__(256) void k_agg(const __half* __restrict__ hw,
                                             const int* __restrict__ row_off,
                                             const int2* __restrict__ csr,
                                             const float* __restrict__ bias,
                                             __half* __restrict__ out) {
  int wid = threadIdx.x >> 6;
  int lane = threadIdx.x & 63;
  int v = blockIdx.x * 4 + wid;
  if (v >= N_NODES) return;
  int o = row_off[v], e = row_off[v + 1];
  float acc = 0.0f;
  int i = o;
  for (; i + 4 <= e; i += 4) {
    int2 p0 = csr[i + 0];
    int2 p1 = csr[i + 1];
    int2 p2 = csr[i + 2];
    int2 p3 = csr[i + 3];
    float h0 = __half2float(hw[(size_t)p0.x * HID + lane]);
    float h1 = __half2float(hw[(size_t)p1.x * HID + lane]);
    float h2 = __half2float(hw[(size_t)p2.x * HID + lane]);
    float h3 = __half2float(hw[(size_t)p3.x * HID + lane]);
    acc += __int_as_float(p0.y) * h0;
    acc += __int_as_float(p1.y) * h1;
    acc += __int_as_float(p2.y) * h2;
    acc += __int_as_float(p3.y) * h3;
  }
  for (; i < e; ++i) {
    int2 p = csr[i];
    acc += __int_as_float(p.y) * __half2float(hw[(size_t)p.x * HID + lane]);
  }
  out[(size_t)v * HID + lane] = __float2half_rn(fmaxf(acc + bias[lane], 0.0f));
}

// ---------------------------------------------------------------- pooling + MLP

#define POOL_CHUNK 32

__global__ __launch_bounds__(256) void k_pool(const __half* __restrict__ h,
                                              const int* __restrict__ batch,
                                              float* __restrict__ pooled,
                                              int* __restrict__ pcnt) {
  int wid = threadIdx.x >> 6, lane = threadIdx.x & 63;
  int w = blockIdx.x * (blockDim.x >> 6) + wid;
  int v0 = w * POOL_CHUNK;
  if (v0 >= N_NODES) return;
  int vend = min(v0 + POOL_CHUNK, N_NODES);
  int g = batch[v0];
  float acc = 0.0f;
  int cnt = 0;
  for (int v = v0; v < vend; ++v) {
    int gv = batch[v];
    if (gv != g) {
      atomicAdd(&pooled[g * HID + lane], acc);
      if (lane == 0) atomicAdd(&pcnt[g], cnt);
      g = gv; acc = 0.0f; cnt = 0;
    }
    acc += __half2float(h[(size_t)v * HID + lane]);
    ++cnt;
  }
  atomicAdd(&pooled[g * HID + lane], acc);
  if (lane == 0) atomicAdd(&pcnt[g], cnt);
}

__global__ void k_mlp(const float* __restrict__ pooled, const int* __restrict__ pcnt,
                      const float* __restrict__ fc1w, const float* __restrict__ fc1b,
                      const float* __restrict__ fc2w, const float* __restrict__ fc2b,
                      float* __restrict__ out) {
  int g = threadIdx.x;
  if (g >= NUM_GRAPHS) return;
  float inv = 1.0f / fmaxf((float)pcnt[g], 1.0f);
  float hid[10];
  #pragma unroll
  for (int j = 0; j < 10; ++j) hid[j] = fc1b[j];
  for (int k = 0; k < HID; ++k) {
    float p = pooled[g * HID + k] * inv;
    #pragma unroll
    for (int j = 0; j < 10; ++j) hid[j] += p * fc1w[k * 10 + j];
  }
  float o = fc2b[0];
  #pragma unroll
  for (int j = 0; j < 10; ++j) o += fmaxf(hid[j], 0.0f) * fc2w[j];
  out[g] = o;
}

// ---------------------------------------------------------------- launch

extern "C" void kernel_launch(void* const* d_in, const int* in_sizes, int n_in,
                              void* d_out, int out_size, void* d_ws, size_t ws_size,
                              hipStream_t stream) {
  const float* x    = (const float*)d_in[0];
  const int*   ei   = (const int*)d_in[1];      // [2, E]
  const int*   batch= (const int*)d_in[2];
  const float* W1   = (const float*)d_in[3];
  const float* b1   = (const float*)d_in[4];
  const float* W2   = (const float*)d_in[5];
  const float* b2   = (const float*)d_in[6];
  const float* W3   = (const float*)d_in[7];
  const float* b3   = (const float*)d_in[8];
  const float* fc1w = (const float*)d_in[9];
  const float* fc1b = (const float*)d_in[10];
  const float* fc2w = (const float*)d_in[11];
  const float* fc2b = (const float*)d_in[12];

  const int* e_src = ei;
  const int* e_dst = ei + N_EDGES;

  // ---- workspace layout
  char* ws = (char*)d_ws;
  auto alignup = [](size_t o, size_t a) { return (o + a - 1) / a * a; };
  size_t off = 0;
  int*   H      = (int*)(ws + off);  off += (size_t)NB * NB * 4;          // zeroed
  int*   pcnt   = (int*)(ws + off);  off += 128 * 4;                      // zeroed
  float* pooled = (float*)(ws + off); off += 8192 * 4;                    // zeroed
  const int ZERO_N = NB * NB + 128 + 8192;                                // 270464 ints
  int*   S      = (int*)(ws + off);  off += NB * 4;
  int*   bstart = (int*)(ws + off);  off += (NB + 1) * 4;  off = alignup(off, 256);
  int*   OT     = (int*)(ws + off);  off += (size_t)NB * NB * 4;          off = alignup(off, 256);
  int*   row_off= (int*)(ws + off);  off += (size_t)(N_NODES + 1) * 4;    off = alignup(off, 256);
  float* dinv   = (float*)(ws + off); off += (size_t)N_NODES * 4;         off = alignup(off, 256);
  int2*  csr    = (int2*)(ws + off); off += (size_t)CSR_TOT * 8;          off = alignup(off, 256);
  __half* xh    = (__half*)(ws + off); off += (size_t)N_NODES * HID * 2;  off = alignup(off, 256);
  __half* h_a   = (__half*)(ws + off); off += (size_t)N_NODES * HID * 2;  off = alignup(off, 256);
  // staged (build phase) and h_b (layer phase) are disjoint in time -> union
  int2*  staged = (int2*)(ws + off);
  __half* h_b   = (__half*)(ws + off); off += (size_t)N_EDGES * 8;
  (void)ws_size; (void)in_sizes; (void)n_in; (void)out_size;

  const int TB = 256;
  // ---- build
  k_zero   <<<(ZERO_N + TB - 1) / TB, TB, 0, stream>>>(H, ZERO_N);
  k_f2h    <<<(N_NODES * HID / 4 + TB - 1) / TB, TB, 0, stream>>>(x, xh, N_NODES * HID / 4);
  k_b1a    <<<NB, TB, 0, stream>>>(e_dst, H);
  k_colsum <<<NB, TB, 0, stream>>>(H, S);
  k_bscan  <<<1, 512, 0, stream>>>(S, bstart);
  k_rowscan<<<NB, 512, 0, stream>>>(H, bstart, OT);
  k_b1b    <<<NB, TB, 0, stream>>>(e_src, e_dst, OT, staged);
  k_b2a    <<<NBU, TB, 0, stream>>>(staged, bstart, row_off, dinv);
  k_b2b    <<<NBU, TB, 0, stream>>>(staged, bstart, row_off, dinv, csr);

  const int GEMM_GRID = (N_NODES + 63) / 64;   // 1563
  const int AGG_GRID  = (N_NODES + 3) / 4;     // 25000

  // ---- layers (gemm first: agg(h@W) == agg(h)@W, aggregation is linear)
  k_gemm<<<GEMM_GRID, TB, 0, stream>>>(xh, W1, h_a);
  k_agg <<<AGG_GRID, TB, 0, stream>>>(h_a, row_off, csr, b1, h_b);   // staged dead now
  k_gemm<<<GEMM_GRID, TB, 0, stream>>>(h_b, W2, h_a);
  k_agg <<<AGG_GRID, TB, 0, stream>>>(h_a, row_off, csr, b2, h_b);
  k_gemm<<<GEMM_GRID, TB, 0, stream>>>(h_b, W3, h_a);
  k_agg <<<AGG_GRID, TB, 0, stream>>>(h_a, row_off, csr, b3, h_b);

  // ---- pool + MLP
  const int POOL_GRID = ((N_NODES + POOL_CHUNK - 1) / POOL_CHUNK + 3) / 4;
  k_pool<<<POOL_GRID, TB, 0, stream>>>(h_b, batch, pooled, pcnt);
  k_mlp <<<1, 128, 0, stream>>>(pooled, pcnt, fc1w, fc1b, fc2w, fc2b, (float*)d_out);
}

// Round 6
// 287.739 us; speedup vs baseline: 2.0216x; 1.2308x over previous
//
#include <hip/hip_runtime.h>
#include <hip/hip_fp16.h>

#define N_NODES   100000
#define N_EDGES   1600000
#define NUM_GRAPHS 128
#define HID       64

#define NB   512          // buckets (node-space partitions)
#define NPB  196          // nodes per bucket: ceil(100000/512)=196; buckets 0..510 used
#define NBU  511          // used buckets
#define CPE  3125         // edges per binning chunk: 1600000/512
#define CSR_TOT (N_EDGES + N_NODES)   // CSR includes one self entry per node

// ---------------------------------------------------------------- utilities

__global__ void k_zero(int* __restrict__ p, int n) {
  int i = blockIdx.x * blockDim.x + threadIdx.x;
  if (i < n) p[i] = 0;
}

__global__ void k_f2h(const float* __restrict__ in, __half* __restrict__ out, int n4) {
  int i = blockIdx.x * blockDim.x + threadIdx.x;
  if (i >= n4) return;
  float4 v = ((const float4*)in)[i];
  ((__half2*)out)[2 * i]     = __floats2half2_rn(v.x, v.y);
  ((__half2*)out)[2 * i + 1] = __floats2half2_rn(v.z, v.w);
}

// ---------------------------------------------------------------- bucketed CSR build
// B1a: per-chunk bucket histogram -> H[w][b]
__global__ __launch_bounds__(256) void k_b1a(const int* __restrict__ dst, int* __restrict__ H) {
  __shared__ int hist[NB];
  int w = blockIdx.x, t = threadIdx.x;
  for (int b = t; b < NB; b += 256) hist[b] = 0;
  __syncthreads();
  int e0 = w * CPE;
  for (int i = t; i < CPE; i += 256)
    atomicAdd(&hist[dst[e0 + i] / NPB], 1);
  __syncthreads();
  for (int b = t; b < NB; b += 256) H[w * NB + b] = hist[b];
}

// column sums: S[b] = sum_w H[w][b]
__global__ __launch_bounds__(256) void k_colsum(const int* __restrict__ H, int* __restrict__ S) {
  __shared__ int red[256];
  int b = blockIdx.x, t = threadIdx.x;
  red[t] = H[t * NB + b] + H[(t + 256) * NB + b];
  __syncthreads();
  for (int d = 128; d > 0; d >>= 1) { if (t < d) red[t] += red[t + d]; __syncthreads(); }
  if (t == 0) S[b] = red[0];
}

// rowscan (+ folded bucket scan): OT[b][w] = bstart[b] + sum_{w'<w} H[w'][b];
// every block redundantly scans S in LDS (trivial); block b also publishes bstart[b].
__global__ __launch_bounds__(512) void k_rowscan(const int* __restrict__ H,
                                                 const int* __restrict__ S,
                                                 int* __restrict__ bstart,
                                                 int* __restrict__ OT) {
  __shared__ int sb[NB];
  __shared__ int sc[NB];
  int b = blockIdx.x, t = threadIdx.x;
  int sv = S[t];
  sb[t] = sv; __syncthreads();
  for (int d = 1; d < NB; d <<= 1) {
    int x = (t >= d) ? sb[t - d] : 0; __syncthreads();
    sb[t] += x; __syncthreads();
  }
  int bst = sb[b] - S[b];            // exclusive scan at this block's bucket
  if (t == 0) bstart[b] = bst;
  if (b == NB - 1 && t == 0) bstart[NB] = sb[NB - 1];
  int v = H[t * NB + b];
  sc[t] = v; __syncthreads();
  for (int d = 1; d < NB; d <<= 1) {
    int x = (t >= d) ? sc[t - d] : 0; __syncthreads();
    sc[t] += x; __syncthreads();
  }
  OT[b * NB + t] = bst + sc[t] - v;
}

// B1b: bin edges into bucket-contiguous staging (contiguous runs per (b,w))
__global__ __launch_bounds__(256) void k_b1b(const int* __restrict__ src,
                                             const int* __restrict__ dst,
                                             const int* __restrict__ OT,
                                             int2* __restrict__ staged) {
  __shared__ int pos[NB];
  int w = blockIdx.x, t = threadIdx.x;
  for (int b = t; b < NB; b += 256) pos[b] = OT[b * NB + w];
  __syncthreads();
  int e0 = w * CPE;
  for (int i = t; i < CPE; i += 256) {
    int s = src[e0 + i], d = dst[e0 + i];
    int p = atomicAdd(&pos[d / NPB], 1);
    staged[p] = make_int2(s, d);
  }
}

// B2a: per-bucket LDS node counts -> monotone row_off (+1 self slot per node) + dinv
__global__ __launch_bounds__(256) void k_b2a(const int2* __restrict__ staged,
                                             const int* __restrict__ bstart,
                                             int* __restrict__ row_off,
                                             float* __restrict__ dinv) {
  __shared__ int cnt[256];
  __shared__ int sc[256];
  int b = blockIdx.x, t = threadIdx.x;
  int nloc = min(NPB, N_NODES - b * NPB);
  cnt[t] = 0;
  __syncthreads();
  int s0 = bstart[b], s1 = bstart[b + 1];
  for (int i = s0 + t; i < s1; i += 256)
    atomicAdd(&cnt[staged[i].y - b * NPB], 1);
  __syncthreads();
  int v = (t < nloc) ? cnt[t] + 1 : 0;   // +1: self-loop CSR entry
  sc[t] = v; __syncthreads();
  for (int d = 1; d < 256; d <<= 1) {
    int x = (t >= d) ? sc[t - d] : 0; __syncthreads();
    sc[t] += x; __syncthreads();
  }
  if (t < nloc) {
    int g = b * NPB + t;
    row_off[g] = bstart[b] + b * NPB + (sc[t] - v);
    dinv[g] = rsqrtf((float)(cnt[t] + 1));   // deg = indeg + self-loop
  }
  if (b == 0 && t == 0) row_off[N_NODES] = CSR_TOT;
}

// B2b: place final (src, norm) entries; self entry first; window is L2-resident
__global__ __launch_bounds__(256) void k_b2b(const int2* __restrict__ staged,
                                             const int* __restrict__ bstart,
                                             const int* __restrict__ row_off,
                                             const float* __restrict__ dinv,
                                             int2* __restrict__ csr) {
  __shared__ int pos[NPB];
  __shared__ float dl[NPB];
  int b = blockIdx.x, t = threadIdx.x;
  int nloc = min(NPB, N_NODES - b * NPB);
  if (t < nloc) {
    int g = b * NPB + t;
    int ro = row_off[g];
    float dv = dinv[g];
    csr[ro] = make_int2(g, __float_as_int(dv * dv));   // self-loop entry
    pos[t] = ro + 1;
    dl[t] = dv;
  }
  __syncthreads();
  int s0 = bstart[b], s1 = bstart[b + 1];
  for (int i = s0 + t; i < s1; i += 256) {
    int2 e = staged[i];
    int l = e.y - b * NPB;
    int p = atomicAdd(&pos[l], 1);
    csr[p] = make_int2(e.x, __float_as_int(dl[l] * dinv[e.x]));
  }
}

// ---------------------------------------------------------------- dense GEMM (fp16 in/out)

__global__ __launch_bounds__(256) void k_gemm(const __half* __restrict__ A,
                                              const float* __restrict__ W,
                                              __half* __restrict__ C) {
  __shared__ float sW[64 * 64];
  __shared__ float sA[64][65];
  int tid = threadIdx.x;
  #pragma unroll
  for (int i = tid; i < 1024; i += 256)
    ((float4*)sW)[i] = ((const float4*)W)[i];
  int row0 = blockIdx.x * 64;
  #pragma unroll
  for (int i = tid; i < 1024; i += 256) {
    int r = i >> 4, c4 = (i & 15) << 2;
    int row = row0 + r;
    if (row < N_NODES) {
      __half2 a = *(const __half2*)(A + (size_t)row * 64 + c4);
      __half2 b = *(const __half2*)(A + (size_t)row * 64 + c4 + 2);
      float2 fa = __half22float2(a), fb = __half22float2(b);
      sA[r][c4 + 0] = fa.x; sA[r][c4 + 1] = fa.y;
      sA[r][c4 + 2] = fb.x; sA[r][c4 + 3] = fb.y;
    } else {
      sA[r][c4 + 0] = 0.f; sA[r][c4 + 1] = 0.f; sA[r][c4 + 2] = 0.f; sA[r][c4 + 3] = 0.f;
    }
  }
  __syncthreads();
  int tr = (tid >> 4) << 2;
  int tc = (tid & 15) << 2;
  float acc[4][4];
  #pragma unroll
  for (int i = 0; i < 4; ++i)
    #pragma unroll
    for (int j = 0; j < 4; ++j) acc[i][j] = 0.f;
  #pragma unroll 8
  for (int k = 0; k < 64; ++k) {
    float4 w = *(const float4*)&sW[k * 64 + tc];
    float a0 = sA[tr + 0][k], a1 = sA[tr + 1][k], a2 = sA[tr + 2][k], a3 = sA[tr + 3][k];
    acc[0][0] += a0 * w.x; acc[0][1] += a0 * w.y; acc[0][2] += a0 * w.z; acc[0][3] += a0 * w.w;
    acc[1][0] += a1 * w.x; acc[1][1] += a1 * w.y; acc[1][2] += a1 * w.z; acc[1][3] += a1 * w.w;
    acc[2][0] += a2 * w.x; acc[2][1] += a2 * w.y; acc[2][2] += a2 * w.z; acc[2][3] += a2 * w.w;
    acc[3][0] += a3 * w.x; acc[3][1] += a3 * w.y; acc[3][2] += a3 * w.z; acc[3][3] += a3 * w.w;
  }
  #pragma unroll
  for (int i = 0; i < 4; ++i) {
    int row = row0 + tr + i;
    if (row < N_NODES) {
      *(__half2*)(C + (size_t)row * 64 + tc)     = __floats2half2_rn(acc[i][0], acc[i][1]);
      *(__half2*)(C + (size_t)row * 64 + tc + 2) = __floats2half2_rn(acc[i][2], acc[i][3]);
    }
  }
}

// ---------------------------------------------------------------- aggregation
// 2 nodes per wave: 32 lanes per node, each lane owns 2 features (__half2).
// Per wave-iteration: two CSR entries (one per half-wave) are served by a
// single gather instruction -> 2x VALU efficiency, 2x loads in flight.

__global__ __launch_bounds__(256) void k_agg(const __half2* __restrict__ hw2,
                                             const int* __restrict__ row_off,
                                             const int2* __restrict__ csr,
                                             const float2* __restrict__ bias2,
                                             __half2* __restrict__ out2) {
  int tid = threadIdx.x;
  int half_id = tid >> 5;           // 8 half-waves per block -> 8 nodes per block
  int f = tid & 31;                 // half2 index: features 2f, 2f+1
  int v = blockIdx.x * 8 + half_id;
  if (v >= N_NODES) return;
  int o = row_off[v], e = row_off[v + 1];
  float accx = 0.f, accy = 0.f;
  int i = o;
  for (; i + 4 <= e; i += 4) {
    int2 p0 = csr[i + 0];
    int2 p1 = csr[i + 1];
    int2 p2 = csr[i + 2];
    int2 p3 = csr[i + 3];
    float2 h0 = __half22float2(hw2[(size_t)p0.x * 32 + f]);
    float2 h1 = __half22float2(hw2[(size_t)p1.x * 32 + f]);
    float2 h2 = __half22float2(hw2[(size_t)p2.x * 32 + f]);
    float2 h3 = __half22float2(hw2[(size_t)p3.x * 32 + f]);
    float n0 = __int_as_float(p0.y), n1 = __int_as_float(p1.y);
    float n2 = __int_as_float(p2.y), n3 = __int_as_float(p3.y);
    accx += n0 * h0.x; accy += n0 * h0.y;
    accx += n1 * h1.x; accy += n1 * h1.y;
    accx += n2 * h2.x; accy += n2 * h2.y;
    accx += n3 * h3.x; accy += n3 * h3.y;
  }
  for (; i < e; ++i) {
    int2 p = csr[i];
    float2 h = __half22float2(hw2[(size_t)p.x * 32 + f]);
    float n = __int_as_float(p.y);
    accx += n * h.x; accy += n * h.y;
  }
  float2 b = bias2[f];
  out2[(size_t)v * 32 + f] =
      __floats2half2_rn(fmaxf(accx + b.x, 0.f), fmaxf(accy + b.y, 0.f));
}

// ---------------------------------------------------------------- pooling + MLP

#define POOL_CHUNK 32

__global__ __launch_bounds__(256) void k_pool(const __half* __restrict__ h,
                                              const int* __restrict__ batch,
                                              float* __restrict__ pooled,
                                              int* __restrict__ pcnt) {
  int wid = threadIdx.x >> 6, lane = threadIdx.x & 63;
  int w = blockIdx.x * (blockDim.x >> 6) + wid;
  int v0 = w * POOL_CHUNK;
  if (v0 >= N_NODES) return;
  int vend = min(v0 + POOL_CHUNK, N_NODES);
  int g = batch[v0];
  float acc = 0.0f;
  int cnt = 0;
  for (int v = v0; v < vend; ++v) {
    int gv = batch[v];
    if (gv != g) {
      atomicAdd(&pooled[g * HID + lane], acc);
      if (lane == 0) atomicAdd(&pcnt[g], cnt);
      g = gv; acc = 0.0f; cnt = 0;
    }
    acc += __half2float(h[(size_t)v * HID + lane]);
    ++cnt;
  }
  atomicAdd(&pooled[g * HID + lane], acc);
  if (lane == 0) atomicAdd(&pcnt[g], cnt);
}

__global__ void k_mlp(const float* __restrict__ pooled, const int* __restrict__ pcnt,
                      const float* __restrict__ fc1w, const float* __restrict__ fc1b,
                      const float* __restrict__ fc2w, const float* __restrict__ fc2b,
                      float* __restrict__ out) {
  int g = threadIdx.x;
  if (g >= NUM_GRAPHS) return;
  float inv = 1.0f / fmaxf((float)pcnt[g], 1.0f);
  float hid[10];
  #pragma unroll
  for (int j = 0; j < 10; ++j) hid[j] = fc1b[j];
  for (int k = 0; k < HID; ++k) {
    float p = pooled[g * HID + k] * inv;
    #pragma unroll
    for (int j = 0; j < 10; ++j) hid[j] += p * fc1w[k * 10 + j];
  }
  float o = fc2b[0];
  #pragma unroll
  for (int j = 0; j < 10; ++j) o += fmaxf(hid[j], 0.0f) * fc2w[j];
  out[g] = o;
}

// ---------------------------------------------------------------- launch

extern "C" void kernel_launch(void* const* d_in, const int* in_sizes, int n_in,
                              void* d_out, int out_size, void* d_ws, size_t ws_size,
                              hipStream_t stream) {
  const float* x    = (const float*)d_in[0];
  const int*   ei   = (const int*)d_in[1];      // [2, E]
  const int*   batch= (const int*)d_in[2];
  const float* W1   = (const float*)d_in[3];
  const float* b1   = (const float*)d_in[4];
  const float* W2   = (const float*)d_in[5];
  const float* b2   = (const float*)d_in[6];
  const float* W3   = (const float*)d_in[7];
  const float* b3   = (const float*)d_in[8];
  const float* fc1w = (const float*)d_in[9];
  const float* fc1b = (const float*)d_in[10];
  const float* fc2w = (const float*)d_in[11];
  const float* fc2b = (const float*)d_in[12];

  const int* e_src = ei;
  const int* e_dst = ei + N_EDGES;

  // ---- workspace layout
  char* ws = (char*)d_ws;
  auto alignup = [](size_t o, size_t a) { return (o + a - 1) / a * a; };
  size_t off = 0;
  int*   H      = (int*)(ws + off);  off += (size_t)NB * NB * 4;          // zeroed
  int*   pcnt   = (int*)(ws + off);  off += 128 * 4;                      // zeroed
  float* pooled = (float*)(ws + off); off += 8192 * 4;                    // zeroed
  const int ZERO_N = NB * NB + 128 + 8192;                                // 270464 ints
  int*   S      = (int*)(ws + off);  off += NB * 4;
  int*   bstart = (int*)(ws + off);  off += (NB + 1) * 4;  off = alignup(off, 256);
  int*   OT     = (int*)(ws + off);  off += (size_t)NB * NB * 4;          off = alignup(off, 256);
  int*   row_off= (int*)(ws + off);  off += (size_t)(N_NODES + 1) * 4;    off = alignup(off, 256);
  float* dinv   = (float*)(ws + off); off += (size_t)N_NODES * 4;         off = alignup(off, 256);
  int2*  csr    = (int2*)(ws + off); off += (size_t)CSR_TOT * 8;          off = alignup(off, 256);
  __half* xh    = (__half*)(ws + off); off += (size_t)N_NODES * HID * 2;  off = alignup(off, 256);
  __half* h_a   = (__half*)(ws + off); off += (size_t)N_NODES * HID * 2;  off = alignup(off, 256);
  // staged (build phase) and h_b (layer phase) are disjoint in time -> union
  int2*  staged = (int2*)(ws + off);
  __half* h_b   = (__half*)(ws + off); off += (size_t)N_EDGES * 8;
  (void)ws_size; (void)in_sizes; (void)n_in; (void)out_size;

  const int TB = 256;
  // ---- build
  k_zero   <<<(ZERO_N + TB - 1) / TB, TB, 0, stream>>>(H, ZERO_N);
  k_f2h    <<<(N_NODES * HID / 4 + TB - 1) / TB, TB, 0, stream>>>(x, xh, N_NODES * HID / 4);
  k_b1a    <<<NB, TB, 0, stream>>>(e_dst, H);
  k_colsum <<<NB, TB, 0, stream>>>(H, S);
  k_rowscan<<<NB, 512, 0, stream>>>(H, S, bstart, OT);
  k_b1b    <<<NB, TB, 0, stream>>>(e_src, e_dst, OT, staged);
  k_b2a    <<<NBU, TB, 0, stream>>>(staged, bstart, row_off, dinv);
  k_b2b    <<<NBU, TB, 0, stream>>>(staged, bstart, row_off, dinv, csr);

  const int GEMM_GRID = (N_NODES + 63) / 64;   // 1563
  const int AGG_GRID  = (N_NODES + 7) / 8;     // 12500 (8 nodes per block)

  // ---- layers (gemm first: agg(h@W) == agg(h)@W, aggregation is linear)
  k_gemm<<<GEMM_GRID, TB, 0, stream>>>(xh, W1, h_a);
  k_agg <<<AGG_GRID, TB, 0, stream>>>((const __half2*)h_a, row_off, csr,
                                      (const float2*)b1, (__half2*)h_b);
  k_gemm<<<GEMM_GRID, TB, 0, stream>>>(h_b, W2, h_a);
  k_agg <<<AGG_GRID, TB, 0, stream>>>((const __half2*)h_a, row_off, csr,
                                      (const float2*)b2, (__half2*)h_b);
  k_gemm<<<GEMM_GRID, TB, 0, stream>>>(h_b, W3, h_a);
  k_agg <<<AGG_GRID, TB, 0, stream>>>((const __half2*)h_a, row_off, csr,
                                      (const float2*)b3, (__half2*)h_b);

  // ---- pool + MLP
  const int POOL_GRID = ((N_NODES + POOL_CHUNK - 1) / POOL_CHUNK + 3) / 4;
  k_pool<<<POOL_GRID, TB, 0, stream>>>(h_b, batch, pooled, pcnt);
  k_mlp <<<1, 128, 0, stream>>>(pooled, pcnt, fc1w, fc1b, fc2w, fc2b, (float*)d_out);
}

// Round 7
// 275.408 us; speedup vs baseline: 2.1122x; 1.0448x over previous
//
#include <hip/hip_runtime.h>
#include <hip/hip_fp16.h>

#define N_NODES   100000
#define N_EDGES   1600000
#define NUM_GRAPHS 128
#define HID       64

#define NB   512          // buckets (node-space partitions)
#define NPB  196          // nodes per bucket: ceil(100000/512)=196; buckets 0..510 used
#define NBU  511          // used buckets
#define CPE  3125         // edges per binning chunk: 1600000/512
#define CSR_TOT (N_EDGES + N_NODES)   // CSR includes one self entry per node

// ---------------------------------------------------------------- utilities

__global__ void k_zero(int* __restrict__ p, int n) {
  int i = blockIdx.x * blockDim.x + threadIdx.x;
  if (i < n) p[i] = 0;
}

__global__ void k_f2h(const float* __restrict__ in, __half* __restrict__ out, int n4) {
  int i = blockIdx.x * blockDim.x + threadIdx.x;
  if (i >= n4) return;
  float4 v = ((const float4*)in)[i];
  ((__half2*)out)[2 * i]     = __floats2half2_rn(v.x, v.y);
  ((__half2*)out)[2 * i + 1] = __floats2half2_rn(v.z, v.w);
}

// ---------------------------------------------------------------- bucketed CSR build
// B1a: per-chunk bucket histogram -> H[w][b]
__global__ __launch_bounds__(256) void k_b1a(const int* __restrict__ dst, int* __restrict__ H) {
  __shared__ int hist[NB];
  int w = blockIdx.x, t = threadIdx.x;
  for (int b = t; b < NB; b += 256) hist[b] = 0;
  __syncthreads();
  int e0 = w * CPE;
  for (int i = t; i < CPE; i += 256)
    atomicAdd(&hist[dst[e0 + i] / NPB], 1);
  __syncthreads();
  for (int b = t; b < NB; b += 256) H[w * NB + b] = hist[b];
}

// column sums: S[b] = sum_w H[w][b]
__global__ __launch_bounds__(256) void k_colsum(const int* __restrict__ H, int* __restrict__ S) {
  __shared__ int red[256];
  int b = blockIdx.x, t = threadIdx.x;
  red[t] = H[t * NB + b] + H[(t + 256) * NB + b];
  __syncthreads();
  for (int d = 128; d > 0; d >>= 1) { if (t < d) red[t] += red[t + d]; __syncthreads(); }
  if (t == 0) S[b] = red[0];
}

// rowscan (+ folded bucket scan): OT[b][w] = bstart[b] + sum_{w'<w} H[w'][b]
__global__ __launch_bounds__(512) void k_rowscan(const int* __restrict__ H,
                                                 const int* __restrict__ S,
                                                 int* __restrict__ bstart,
                                                 int* __restrict__ OT) {
  __shared__ int sb[NB];
  __shared__ int sc[NB];
  int b = blockIdx.x, t = threadIdx.x;
  int sv = S[t];
  sb[t] = sv; __syncthreads();
  for (int d = 1; d < NB; d <<= 1) {
    int x = (t >= d) ? sb[t - d] : 0; __syncthreads();
    sb[t] += x; __syncthreads();
  }
  int bst = sb[b] - S[b];
  if (t == 0) bstart[b] = bst;
  if (b == NB - 1 && t == 0) bstart[NB] = sb[NB - 1];
  int v = H[t * NB + b];
  sc[t] = v; __syncthreads();
  for (int d = 1; d < NB; d <<= 1) {
    int x = (t >= d) ? sc[t - d] : 0; __syncthreads();
    sc[t] += x; __syncthreads();
  }
  OT[b * NB + t] = bst + sc[t] - v;
}

// B1b: bin edges into bucket-contiguous staging
__global__ __launch_bounds__(256) void k_b1b(const int* __restrict__ src,
                                             const int* __restrict__ dst,
                                             const int* __restrict__ OT,
                                             int2* __restrict__ staged) {
  __shared__ int pos[NB];
  int w = blockIdx.x, t = threadIdx.x;
  for (int b = t; b < NB; b += 256) pos[b] = OT[b * NB + w];
  __syncthreads();
  int e0 = w * CPE;
  for (int i = t; i < CPE; i += 256) {
    int s = src[e0 + i], d = dst[e0 + i];
    int p = atomicAdd(&pos[d / NPB], 1);
    staged[p] = make_int2(s, d);
  }
}

// B2a: per-bucket LDS node counts -> monotone row_off (+1 self slot per node) + dinv
__global__ __launch_bounds__(256) void k_b2a(const int2* __restrict__ staged,
                                             const int* __restrict__ bstart,
                                             int* __restrict__ row_off,
                                             float* __restrict__ dinv) {
  __shared__ int cnt[256];
  __shared__ int sc[256];
  int b = blockIdx.x, t = threadIdx.x;
  int nloc = min(NPB, N_NODES - b * NPB);
  cnt[t] = 0;
  __syncthreads();
  int s0 = bstart[b], s1 = bstart[b + 1];
  for (int i = s0 + t; i < s1; i += 256)
    atomicAdd(&cnt[staged[i].y - b * NPB], 1);
  __syncthreads();
  int v = (t < nloc) ? cnt[t] + 1 : 0;   // +1: self-loop CSR entry
  sc[t] = v; __syncthreads();
  for (int d = 1; d < 256; d <<= 1) {
    int x = (t >= d) ? sc[t - d] : 0; __syncthreads();
    sc[t] += x; __syncthreads();
  }
  if (t < nloc) {
    int g = b * NPB + t;
    row_off[g] = bstart[b] + b * NPB + (sc[t] - v);
    dinv[g] = rsqrtf((float)(cnt[t] + 1));
  }
  if (b == 0 && t == 0) row_off[N_NODES] = CSR_TOT;
}

// B2b: place final (src, norm) entries; self entry first
__global__ __launch_bounds__(256) void k_b2b(const int2* __restrict__ staged,
                                             const int* __restrict__ bstart,
                                             const int* __restrict__ row_off,
                                             const float* __restrict__ dinv,
                                             int2* __restrict__ csr) {
  __shared__ int pos[NPB];
  __shared__ float dl[NPB];
  int b = blockIdx.x, t = threadIdx.x;
  int nloc = min(NPB, N_NODES - b * NPB);
  if (t < nloc) {
    int g = b * NPB + t;
    int ro = row_off[g];
    float dv = dinv[g];
    csr[ro] = make_int2(g, __float_as_int(dv * dv));
    pos[t] = ro + 1;
    dl[t] = dv;
  }
  __syncthreads();
  int s0 = bstart[b], s1 = bstart[b + 1];
  for (int i = s0 + t; i < s1; i += 256) {
    int2 e = staged[i];
    int l = e.y - b * NPB;
    int p = atomicAdd(&pos[l], 1);
    csr[p] = make_int2(e.x, __float_as_int(dl[l] * dinv[e.x]));
  }
}

// ---------------------------------------------------------------- degree sort
// counting sort by (clamped) degree so each agg wave gets 8 equal-degree nodes.

__global__ __launch_bounds__(256) void k_dhist(const int* __restrict__ row_off,
                                               int* __restrict__ dbins) {
  __shared__ int h[256];
  int t = threadIdx.x;
  h[t] = 0;
  __syncthreads();
  int v = blockIdx.x * 256 + t;
  if (v < N_NODES) {
    int deg = min(row_off[v + 1] - row_off[v], 255);
    atomicAdd(&h[deg], 1);
  }
  __syncthreads();
  if (h[t] > 0) atomicAdd(&dbins[t], h[t]);
}

__global__ __launch_bounds__(256) void k_dscan(const int* __restrict__ dbins,
                                               int* __restrict__ dpos) {
  __shared__ int sc[256];
  int t = threadIdx.x;
  int v = dbins[t];
  sc[t] = v; __syncthreads();
  for (int d = 1; d < 256; d <<= 1) {
    int x = (t >= d) ? sc[t - d] : 0; __syncthreads();
    sc[t] += x; __syncthreads();
  }
  dpos[t] = sc[t] - v;   // exclusive
}

__global__ __launch_bounds__(256) void k_dperm(const int* __restrict__ row_off,
                                               int* __restrict__ dpos,
                                               int* __restrict__ perm) {
  __shared__ int cnt[256];
  __shared__ int sbase[256];
  int t = threadIdx.x;
  cnt[t] = 0;
  __syncthreads();
  int v = blockIdx.x * 256 + t;
  int bin = 0, rank = 0;
  if (v < N_NODES) {
    bin = min(row_off[v + 1] - row_off[v], 255);
    rank = atomicAdd(&cnt[bin], 1);
  }
  __syncthreads();
  if (cnt[t] > 0) sbase[t] = atomicAdd(&dpos[t], cnt[t]);
  __syncthreads();
  if (v < N_NODES) perm[sbase[bin] + rank] = v;
}

// ---------------------------------------------------------------- dense GEMM (fp16 in/out)

__global__ __launch_bounds__(256) void k_gemm(const __half* __restrict__ A,
                                              const float* __restrict__ W,
                                              __half* __restrict__ C) {
  __shared__ float sW[64 * 64];
  __shared__ float sA[64][65];
  int tid = threadIdx.x;
  #pragma unroll
  for (int i = tid; i < 1024; i += 256)
    ((float4*)sW)[i] = ((const float4*)W)[i];
  int row0 = blockIdx.x * 64;
  #pragma unroll
  for (int i = tid; i < 1024; i += 256) {
    int r = i >> 4, c4 = (i & 15) << 2;
    int row = row0 + r;
    if (row < N_NODES) {
      __half2 a = *(const __half2*)(A + (size_t)row * 64 + c4);
      __half2 b = *(const __half2*)(A + (size_t)row * 64 + c4 + 2);
      float2 fa = __half22float2(a), fb = __half22float2(b);
      sA[r][c4 + 0] = fa.x; sA[r][c4 + 1] = fa.y;
      sA[r][c4 + 2] = fb.x; sA[r][c4 + 3] = fb.y;
    } else {
      sA[r][c4 + 0] = 0.f; sA[r][c4 + 1] = 0.f; sA[r][c4 + 2] = 0.f; sA[r][c4 + 3] = 0.f;
    }
  }
  __syncthreads();
  int tr = (tid >> 4) << 2;
  int tc = (tid & 15) << 2;
  float acc[4][4];
  #pragma unroll
  for (int i = 0; i < 4; ++i)
    #pragma unroll
    for (int j = 0; j < 4; ++j) acc[i][j] = 0.f;
  #pragma unroll 8
  for (int k = 0; k < 64; ++k) {
    float4 w = *(const float4*)&sW[k * 64 + tc];
    float a0 = sA[tr + 0][k], a1 = sA[tr + 1][k], a2 = sA[tr + 2][k], a3 = sA[tr + 3][k];
    acc[0][0] += a0 * w.x; acc[0][1] += a0 * w.y; acc[0][2] += a0 * w.z; acc[0][3] += a0 * w.w;
    acc[1][0] += a1 * w.x; acc[1][1] += a1 * w.y; acc[1][2] += a1 * w.z; acc[1][3] += a1 * w.w;
    acc[2][0] += a2 * w.x; acc[2][1] += a2 * w.y; acc[2][2] += a2 * w.z; acc[2][3] += a2 * w.w;
    acc[3][0] += a3 * w.x; acc[3][1] += a3 * w.y; acc[3][2] += a3 * w.z; acc[3][3] += a3 * w.w;
  }
  #pragma unroll
  for (int i = 0; i < 4; ++i) {
    int row = row0 + tr + i;
    if (row < N_NODES) {
      *(__half2*)(C + (size_t)row * 64 + tc)     = __floats2half2_rn(acc[i][0], acc[i][1]);
      *(__half2*)(C + (size_t)row * 64 + tc + 2) = __floats2half2_rn(acc[i][2], acc[i][3]);
    }
  }
}

// ---------------------------------------------------------------- aggregation
// 8 nodes per wave (degree-sorted), 8 lanes per node, 16B (8 features) per lane.
// One gather instruction fetches 8 full rows (1KB). Lane-local accumulation,
// no cross-lane reduce. Branch-free predication via index clamp + zeroed norm.

__device__ __forceinline__ void fma8(float* acc, float n, uint4 h) {
  __half2 u0 = *(__half2*)&h.x, u1 = *(__half2*)&h.y;
  __half2 u2 = *(__half2*)&h.z, u3 = *(__half2*)&h.w;
  float2 f0 = __half22float2(u0), f1 = __half22float2(u1);
  float2 f2 = __half22float2(u2), f3 = __half22float2(u3);
  acc[0] = fmaf(n, f0.x, acc[0]); acc[1] = fmaf(n, f0.y, acc[1]);
  acc[2] = fmaf(n, f1.x, acc[2]); acc[3] = fmaf(n, f1.y, acc[3]);
  acc[4] = fmaf(n, f2.x, acc[4]); acc[5] = fmaf(n, f2.y, acc[5]);
  acc[6] = fmaf(n, f3.x, acc[6]); acc[7] = fmaf(n, f3.y, acc[7]);
}

__global__ __launch_bounds__(256) void k_agg(const __half* __restrict__ hw,
                                             const int* __restrict__ row_off,
                                             const int2* __restrict__ csr,
                                             const int* __restrict__ perm,
                                             const float* __restrict__ bias,
                                             __half* __restrict__ out) {
  int tid = threadIdx.x;
  int lane = tid & 63;
  int sg = lane >> 3;            // subgroup = node slot within wave
  int k = lane & 7;              // 16B chunk (8 features) within row
  int slot = (blockIdx.x * 4 + (tid >> 6)) * 8 + sg;
  int v = -1, o = 0, d = 1;
  if (slot < N_NODES) {
    v = perm[slot];
    o = row_off[v];
    d = row_off[v + 1] - o;      // >= 1 (self entry)
  }
  int m = d;
  m = max(m, __shfl_xor(m, 8));
  m = max(m, __shfl_xor(m, 16));
  m = max(m, __shfl_xor(m, 32));
  float acc[8];
  #pragma unroll
  for (int j = 0; j < 8; ++j) acc[j] = 0.f;
  const __half* hk = hw + k * 8;
  int dm1 = d - 1;
  int i = 0;
  for (; i + 4 <= m; i += 4) {
    int2 p0 = csr[o + min(i + 0, dm1)];
    int2 p1 = csr[o + min(i + 1, dm1)];
    int2 p2 = csr[o + min(i + 2, dm1)];
    int2 p3 = csr[o + min(i + 3, dm1)];
    uint4 h0 = *(const uint4*)(hk + (size_t)p0.x * 64);
    uint4 h1 = *(const uint4*)(hk + (size_t)p1.x * 64);
    uint4 h2 = *(const uint4*)(hk + (size_t)p2.x * 64);
    uint4 h3 = *(const uint4*)(hk + (size_t)p3.x * 64);
    float n0 = (i + 0 < d) ? __int_as_float(p0.y) : 0.f;
    float n1 = (i + 1 < d) ? __int_as_float(p1.y) : 0.f;
    float n2 = (i + 2 < d) ? __int_as_float(p2.y) : 0.f;
    float n3 = (i + 3 < d) ? __int_as_float(p3.y) : 0.f;
    fma8(acc, n0, h0);
    fma8(acc, n1, h1);
    fma8(acc, n2, h2);
    fma8(acc, n3, h3);
  }
  for (; i < m; ++i) {
    int2 p = csr[o + min(i, dm1)];
    uint4 h = *(const uint4*)(hk + (size_t)p.x * 64);
    float n = (i < d) ? __int_as_float(p.y) : 0.f;
    fma8(acc, n, h);
  }
  if (v >= 0) {
    float4 b0 = *(const float4*)(bias + k * 8);
    float4 b1 = *(const float4*)(bias + k * 8 + 4);
    __half2 q0 = __floats2half2_rn(fmaxf(acc[0] + b0.x, 0.f), fmaxf(acc[1] + b0.y, 0.f));
    __half2 q1 = __floats2half2_rn(fmaxf(acc[2] + b0.z, 0.f), fmaxf(acc[3] + b0.w, 0.f));
    __half2 q2 = __floats2half2_rn(fmaxf(acc[4] + b1.x, 0.f), fmaxf(acc[5] + b1.y, 0.f));
    __half2 q3 = __floats2half2_rn(fmaxf(acc[6] + b1.z, 0.f), fmaxf(acc[7] + b1.w, 0.f));
    uint4 r;
    r.x = *(unsigned int*)&q0; r.y = *(unsigned int*)&q1;
    r.z = *(unsigned int*)&q2; r.w = *(unsigned int*)&q3;
    *(uint4*)(out + (size_t)v * HID + k * 8) = r;
  }
}

// ---------------------------------------------------------------- pooling + MLP

#define POOL_CHUNK 32

__global__ __launch_bounds__(256) void k_pool(const __half* __restrict__ h,
                                              const int* __restrict__ batch,
                                              float* __restrict__ pooled,
                                              int* __restrict__ pcnt) {
  int wid = threadIdx.x >> 6, lane = threadIdx.x & 63;
  int w = blockIdx.x * (blockDim.x >> 6) + wid;
  int v0 = w * POOL_CHUNK;
  if (v0 >= N_NODES) return;
  int vend = min(v0 + POOL_CHUNK, N_NODES);
  int g = batch[v0];
  float acc = 0.0f;
  int cnt = 0;
  for (int v = v0; v < vend; ++v) {
    int gv = batch[v];
    if (gv != g) {
      atomicAdd(&pooled[g * HID + lane], acc);
      if (lane == 0) atomicAdd(&pcnt[g], cnt);
      g = gv; acc = 0.0f; cnt = 0;
    }
    acc += __half2float(h[(size_t)v * HID + lane]);
    ++cnt;
  }
  atomicAdd(&pooled[g * HID + lane], acc);
  if (lane == 0) atomicAdd(&pcnt[g], cnt);
}

__global__ void k_mlp(const float* __restrict__ pooled, const int* __restrict__ pcnt,
                      const float* __restrict__ fc1w, const float* __restrict__ fc1b,
                      const float* __restrict__ fc2w, const float* __restrict__ fc2b,
                      float* __restrict__ out) {
  int g = threadIdx.x;
  if (g >= NUM_GRAPHS) return;
  float inv = 1.0f / fmaxf((float)pcnt[g], 1.0f);
  float hid[10];
  #pragma unroll
  for (int j = 0; j < 10; ++j) hid[j] = fc1b[j];
  for (int k = 0; k < HID; ++k) {
    float p = pooled[g * HID + k] * inv;
    #pragma unroll
    for (int j = 0; j < 10; ++j) hid[j] += p * fc1w[k * 10 + j];
  }
  float o = fc2b[0];
  #pragma unroll
  for (int j = 0; j < 10; ++j) o += fmaxf(hid[j], 0.0f) * fc2w[j];
  out[g] = o;
}

// ---------------------------------------------------------------- launch

extern "C" void kernel_launch(void* const* d_in, const int* in_sizes, int n_in,
                              void* d_out, int out_size, void* d_ws, size_t ws_size,
                              hipStream_t stream) {
  const float* x    = (const float*)d_in[0];
  const int*   ei   = (const int*)d_in[1];      // [2, E]
  const int*   batch= (const int*)d_in[2];
  const float* W1   = (const float*)d_in[3];
  const float* b1   = (const float*)d_in[4];
  const float* W2   = (const float*)d_in[5];
  const float* b2   = (const float*)d_in[6];
  const float* W3   = (const float*)d_in[7];
  const float* b3   = (const float*)d_in[8];
  const float* fc1w = (const float*)d_in[9];
  const float* fc1b = (const float*)d_in[10];
  const float* fc2w = (const float*)d_in[11];
  const float* fc2b = (const float*)d_in[12];

  const int* e_src = ei;
  const int* e_dst = ei + N_EDGES;

  // ---- workspace layout
  char* ws = (char*)d_ws;
  auto alignup = [](size_t o, size_t a) { return (o + a - 1) / a * a; };
  size_t off = 0;
  int*   H      = (int*)(ws + off);  off += (size_t)NB * NB * 4;          // zeroed
  int*   pcnt   = (int*)(ws + off);  off += 128 * 4;                      // zeroed
  float* pooled = (float*)(ws + off); off += 8192 * 4;                    // zeroed
  int*   dbins  = (int*)(ws + off);  off += 256 * 4;                      // zeroed
  const int ZERO_N = NB * NB + 128 + 8192 + 256;
  int*   S      = (int*)(ws + off);  off += NB * 4;
  int*   bstart = (int*)(ws + off);  off += (NB + 1) * 4;
  int*   dpos   = (int*)(ws + off);  off += 256 * 4;       off = alignup(off, 256);
  int*   OT     = (int*)(ws + off);  off += (size_t)NB * NB * 4;          off = alignup(off, 256);
  int*   row_off= (int*)(ws + off);  off += (size_t)(N_NODES + 1) * 4;    off = alignup(off, 256);
  float* dinv   = (float*)(ws + off); off += (size_t)N_NODES * 4;         off = alignup(off, 256);
  int*   perm   = (int*)(ws + off);  off += (size_t)N_NODES * 4;          off = alignup(off, 256);
  int2*  csr    = (int2*)(ws + off); off += (size_t)CSR_TOT * 8;          off = alignup(off, 256);
  __half* xh    = (__half*)(ws + off); off += (size_t)N_NODES * HID * 2;  off = alignup(off, 256);
  __half* h_a   = (__half*)(ws + off); off += (size_t)N_NODES * HID * 2;  off = alignup(off, 256);
  // staged (build phase) and h_b (layer phase) are disjoint in time -> union
  int2*  staged = (int2*)(ws + off);
  __half* h_b   = (__half*)(ws + off); off += (size_t)N_EDGES * 8;
  (void)ws_size; (void)in_sizes; (void)n_in; (void)out_size;

  const int TB = 256;
  const int NGRID = (N_NODES + TB - 1) / TB;   // 391
  // ---- build
  k_zero   <<<(ZERO_N + TB - 1) / TB, TB, 0, stream>>>(H, ZERO_N);
  k_f2h    <<<(N_NODES * HID / 4 + TB - 1) / TB, TB, 0, stream>>>(x, xh, N_NODES * HID / 4);
  k_b1a    <<<NB, TB, 0, stream>>>(e_dst, H);
  k_colsum <<<NB, TB, 0, stream>>>(H, S);
  k_rowscan<<<NB, 512, 0, stream>>>(H, S, bstart, OT);
  k_b1b    <<<NB, TB, 0, stream>>>(e_src, e_dst, OT, staged);
  k_b2a    <<<NBU, TB, 0, stream>>>(staged, bstart, row_off, dinv);
  k_b2b    <<<NBU, TB, 0, stream>>>(staged, bstart, row_off, dinv, csr);
  // ---- degree sort
  k_dhist  <<<NGRID, TB, 0, stream>>>(row_off, dbins);
  k_dscan  <<<1, TB, 0, stream>>>(dbins, dpos);
  k_dperm  <<<NGRID, TB, 0, stream>>>(row_off, dpos, perm);

  const int GEMM_GRID = (N_NODES + 63) / 64;   // 1563
  const int AGG_GRID  = (N_NODES + 31) / 32;   // 3125 (32 nodes per block)

  // ---- layers (gemm first: agg(h@W) == agg(h)@W, aggregation is linear)
  k_gemm<<<GEMM_GRID, TB, 0, stream>>>(xh, W1, h_a);
  k_agg <<<AGG_GRID, TB, 0, stream>>>(h_a, row_off, csr, perm, b1, h_b);
  k_gemm<<<GEMM_GRID, TB, 0, stream>>>(h_b, W2, h_a);
  k_agg <<<AGG_GRID, TB, 0, stream>>>(h_a, row_off, csr, perm, b2, h_b);
  k_gemm<<<GEMM_GRID, TB, 0, stream>>>(h_b, W3, h_a);
  k_agg <<<AGG_GRID, TB, 0, stream>>>(h_a, row_off, csr, perm, b3, h_b);

  // ---- pool + MLP
  const int POOL_GRID = ((N_NODES + POOL_CHUNK - 1) / POOL_CHUNK + 3) / 4;
  k_pool<<<POOL_GRID, TB, 0, stream>>>(h_b, batch, pooled, pcnt);
  k_mlp <<<1, 128, 0, stream>>>(pooled, pcnt, fc1w, fc1b, fc2w, fc2b, (float*)d_out);
}